// Round 7
// baseline (193.996 us; speedup 1.0000x reference)
//
#include <hip/hip_runtime.h>

#define DF 256   // feature dim
#define MAXB 8   // rows per LDS batch (per array)

typedef float f32x4 __attribute__((ext_vector_type(4)));

// ---- 1. histogram ----
__global__ void cp_count(const int* __restrict__ cmap, int* __restrict__ counts, int n) {
    int i = blockIdx.x * blockDim.x + threadIdx.x;
    if (i < n) atomicAdd(&counts[cmap[i]], 1);
}

// ---- 2a. per-block exclusive scan ----
__global__ void cp_scanA(const int* __restrict__ counts, int* __restrict__ offsets,
                         int* __restrict__ blocksums, int C) {
    __shared__ int s[256];
    int tid = threadIdx.x;
    int i = blockIdx.x * 256 + tid;
    int v = (i < C) ? counts[i] : 0;
    s[tid] = v;
    __syncthreads();
    for (int off = 1; off < 256; off <<= 1) {
        int t = (tid >= off) ? s[tid - off] : 0;
        __syncthreads();
        s[tid] += t;
        __syncthreads();
    }
    if (i < C) offsets[i] = s[tid] - v;
    if (tid == 255) blocksums[blockIdx.x] = s[255];
}

// ---- 2b. scan block sums ----
__global__ void cp_scanB(int* __restrict__ blocksums, int nb) {
    __shared__ int s[256];
    int tid = threadIdx.x;
    if (nb <= 256) {
        int v = (tid < nb) ? blocksums[tid] : 0;
        s[tid] = v;
        __syncthreads();
        for (int off = 1; off < 256; off <<= 1) {
            int t = (tid >= off) ? s[tid - off] : 0;
            __syncthreads();
            s[tid] += t;
            __syncthreads();
        }
        if (tid < nb) blocksums[tid] = s[tid] - v;
    } else if (tid == 0) {
        int run = 0;
        for (int k = 0; k < nb; ++k) { int t = blocksums[k]; blocksums[k] = run; run += t; }
    }
}

// ---- 2c. add block offsets; build fused seg[c] = {start, len} ----
__global__ void cp_scanC(int* __restrict__ offsets, const int* __restrict__ blocksums,
                         const int* __restrict__ counts, int2* __restrict__ seg, int C) {
    int i = blockIdx.x * 256 + threadIdx.x;
    if (i < C) {
        int st = offsets[i] + blocksums[blockIdx.x];
        offsets[i] = st;
        seg[i] = make_int2(st, counts[i]);
    }
}

// ---- 3. bucket-fill ----
__global__ void cp_fill(const int* __restrict__ cmap, const int* __restrict__ offsets,
                        int* __restrict__ cursor, int* __restrict__ node_list, int n) {
    int i = blockIdx.x * blockDim.x + threadIdx.x;
    if (i < n) {
        int c = cmap[i];
        int slot = atomicAdd(&cursor[c], 1);
        node_list[offsets[c] + slot] = i;
    }
}

// ---- 4. pool: one wave per cluster; rows staged via global_load_lds DMA ----
__global__ void __launch_bounds__(256) cp_pool(
        const float* __restrict__ x, const float* __restrict__ h,
        const int2* __restrict__ seg, const int* __restrict__ node_list,
        float* __restrict__ xp, float* __restrict__ hp, int C) {
    // per wave: MAXB x-rows then MAXB h-rows, 256 floats each -> 16 KB/wave, 64 KB/block
    __shared__ float lds[4 * 2 * MAXB * 256];
    int wid  = threadIdx.x >> 6;
    int lane = threadIdx.x & 63;
    int c = blockIdx.x * 4 + wid;
    if (c >= C) return;

    float* wl = lds + wid * (2 * MAXB * 256);

    int2 sl = seg[c];
    int start = sl.x, len = sl.y;

    // preload up to 64 node ids in one coalesced load
    int nid = 0;
    if (lane < len) nid = node_list[start + lane];

    f32x4 ax = 0.f;
    f32x4 ah = 0.f;

    for (int b = 0; b < len; b += MAXB) {
        int nb = len - b; if (nb > MAXB) nb = MAXB;
        // issue DMA: one global_load_lds_dwordx4 per row (1 KB each), no VGPR return
        for (int j = 0; j < nb; ++j) {
            int k = b + j;
            int n = (k < 64) ? __shfl(nid, k) : node_list[start + k];  // wave-uniform
            const float* xrow = x + (size_t)n * DF + lane * 4;
            const float* hrow = h + (size_t)n * DF + lane * 4;
            __builtin_amdgcn_global_load_lds(
                (const __attribute__((address_space(1))) void*)xrow,
                (__attribute__((address_space(3))) void*)(wl + j * 256), 16, 0, 0);
            __builtin_amdgcn_global_load_lds(
                (const __attribute__((address_space(1))) void*)hrow,
                (__attribute__((address_space(3))) void*)(wl + (MAXB + j) * 256), 16, 0, 0);
        }
        asm volatile("s_waitcnt vmcnt(0)" ::: "memory");
        for (int j = 0; j < nb; ++j) {
            ax += *reinterpret_cast<const f32x4*>(wl + j * 256 + lane * 4);
            ah += *reinterpret_cast<const f32x4*>(wl + (MAXB + j) * 256 + lane * 4);
        }
    }

    float inv = 1.0f / (float)(len > 0 ? len : 1);
    f32x4 vx = ax * inv;
    f32x4 vh = ah * inv;
    __builtin_nontemporal_store(vx, reinterpret_cast<f32x4*>(xp + (size_t)c * DF) + lane);
    __builtin_nontemporal_store(vh, reinterpret_cast<f32x4*>(hp + (size_t)c * DF) + lane);
}

// ---- 5. pos gather ----
__global__ void cp_pos(const float* __restrict__ pos, const int* __restrict__ sidx,
                       float* __restrict__ out, int C) {
    int i = blockIdx.x * blockDim.x + threadIdx.x;
    if (i >= C) return;
    int s = sidx[i];
    float p0 = pos[(size_t)s * 3 + 0];
    float p1 = pos[(size_t)s * 3 + 1];
    float p2 = pos[(size_t)s * 3 + 2];
    __builtin_nontemporal_store(p0, &out[(size_t)i * 3 + 0]);
    __builtin_nontemporal_store(p1, &out[(size_t)i * 3 + 1]);
    __builtin_nontemporal_store(p2, &out[(size_t)i * 3 + 2]);
}

extern "C" void kernel_launch(void* const* d_in, const int* in_sizes, int n_in,
                              void* d_out, int out_size, void* d_ws, size_t ws_size,
                              hipStream_t stream) {
    const float* x    = (const float*)d_in[0];
    const float* h    = (const float*)d_in[1];
    const float* pos  = (const float*)d_in[2];
    const int*   cmap = (const int*)d_in[3];
    const int*   sidx = (const int*)d_in[4];

    const int n_nodes = in_sizes[2] / 3;
    const int C       = in_sizes[4];

    float* out  = (float*)d_out;
    float* xp   = out;
    float* hp   = out + (size_t)C * DF;
    float* pout = out + (size_t)2 * C * DF;

    // ws ints: counts[C] | cursor[C] | offsets[C] | blocksums[256] | seg[2C] | node_list[N]
    int*  counts    = (int*)d_ws;
    int*  cursor    = counts + C;
    int*  offsets   = cursor + C;
    int*  blocksums = offsets + C;
    int2* seg       = (int2*)(blocksums + 256);
    int*  node_list = (int*)(seg + C);

    hipMemsetAsync(counts, 0, (size_t)2 * C * sizeof(int), stream);

    cp_count<<<(n_nodes + 255) / 256, 256, 0, stream>>>(cmap, counts, n_nodes);

    int nb = (C + 255) / 256;
    cp_scanA<<<nb, 256, 0, stream>>>(counts, offsets, blocksums, C);
    cp_scanB<<<1, 256, 0, stream>>>(blocksums, nb);
    cp_scanC<<<nb, 256, 0, stream>>>(offsets, blocksums, counts, seg, C);

    cp_fill<<<(n_nodes + 255) / 256, 256, 0, stream>>>(cmap, offsets, cursor, node_list, n_nodes);

    cp_pool<<<(C + 3) / 4, 256, 0, stream>>>(x, h, seg, node_list, xp, hp, C);

    cp_pos<<<(C + 255) / 256, 256, 0, stream>>>(pos, sidx, pout, C);
}

// Round 8
// 131.408 us; speedup vs baseline: 1.4763x; 1.4763x over previous
//
#include <hip/hip_runtime.h>

#define DF 256  // feature dim

typedef float f32x4 __attribute__((ext_vector_type(4)));

// ---- 1. histogram ----
__global__ void cp_count(const int* __restrict__ cmap, int* __restrict__ counts, int n) {
    int i = blockIdx.x * blockDim.x + threadIdx.x;
    if (i < n) atomicAdd(&counts[cmap[i]], 1);
}

// ---- 2a. per-block exclusive scan ----
__global__ void cp_scanA(const int* __restrict__ counts, int* __restrict__ offsets,
                         int* __restrict__ blocksums, int C) {
    __shared__ int s[256];
    int tid = threadIdx.x;
    int i = blockIdx.x * 256 + tid;
    int v = (i < C) ? counts[i] : 0;
    s[tid] = v;
    __syncthreads();
    for (int off = 1; off < 256; off <<= 1) {
        int t = (tid >= off) ? s[tid - off] : 0;
        __syncthreads();
        s[tid] += t;
        __syncthreads();
    }
    if (i < C) offsets[i] = s[tid] - v;
    if (tid == 255) blocksums[blockIdx.x] = s[255];
}

// ---- 2b. scan block sums ----
__global__ void cp_scanB(int* __restrict__ blocksums, int nb) {
    __shared__ int s[256];
    int tid = threadIdx.x;
    if (nb <= 256) {
        int v = (tid < nb) ? blocksums[tid] : 0;
        s[tid] = v;
        __syncthreads();
        for (int off = 1; off < 256; off <<= 1) {
            int t = (tid >= off) ? s[tid - off] : 0;
            __syncthreads();
            s[tid] += t;
            __syncthreads();
        }
        if (tid < nb) blocksums[tid] = s[tid] - v;
    } else if (tid == 0) {
        int run = 0;
        for (int k = 0; k < nb; ++k) { int t = blocksums[k]; blocksums[k] = run; run += t; }
    }
}

// ---- 2c. add block offsets; also build fused seg[c] = {start, len} ----
__global__ void cp_scanC(int* __restrict__ offsets, const int* __restrict__ blocksums,
                         const int* __restrict__ counts, int2* __restrict__ seg, int C) {
    int i = blockIdx.x * 256 + threadIdx.x;
    if (i < C) {
        int st = offsets[i] + blocksums[blockIdx.x];
        offsets[i] = st;
        seg[i] = make_int2(st, counts[i]);
    }
}

// ---- 3. bucket-fill ----
__global__ void cp_fill(const int* __restrict__ cmap, const int* __restrict__ offsets,
                        int* __restrict__ cursor, int* __restrict__ node_list, int n) {
    int i = blockIdx.x * blockDim.x + threadIdx.x;
    if (i < n) {
        int c = cmap[i];
        int slot = atomicAdd(&cursor[c], 1);
        node_list[offsets[c] + slot] = i;
    }
}

// ---- 4. pool: one wave per cluster; NT gather loads + NT stores ----
__global__ void cp_pool(const float* __restrict__ x, const float* __restrict__ h,
                        const int2* __restrict__ seg, const int* __restrict__ node_list,
                        float* __restrict__ xp, float* __restrict__ hp, int C) {
    int c = blockIdx.x * 4 + (threadIdx.x >> 6);
    if (c >= C) return;
    int lane = threadIdx.x & 63;
    int2 sl = seg[c];                      // one 8B load: {start, len}
    int start = sl.x, len = sl.y;

    // preload up to 64 node ids in a single coalesced vector load
    int nid = 0;
    if (lane < len) nid = node_list[start + lane];

    f32x4 ax = 0.f;
    f32x4 ah = 0.f;
    int kmax = len < 64 ? len : 64;
    int k = 0;
    for (; k + 4 <= kmax; k += 4) {
        int n0 = __shfl(nid, k);
        int n1 = __shfl(nid, k + 1);
        int n2 = __shfl(nid, k + 2);
        int n3 = __shfl(nid, k + 3);
        f32x4 x0 = __builtin_nontemporal_load(reinterpret_cast<const f32x4*>(x + (size_t)n0 * DF) + lane);
        f32x4 h0 = __builtin_nontemporal_load(reinterpret_cast<const f32x4*>(h + (size_t)n0 * DF) + lane);
        f32x4 x1 = __builtin_nontemporal_load(reinterpret_cast<const f32x4*>(x + (size_t)n1 * DF) + lane);
        f32x4 h1 = __builtin_nontemporal_load(reinterpret_cast<const f32x4*>(h + (size_t)n1 * DF) + lane);
        f32x4 x2 = __builtin_nontemporal_load(reinterpret_cast<const f32x4*>(x + (size_t)n2 * DF) + lane);
        f32x4 h2 = __builtin_nontemporal_load(reinterpret_cast<const f32x4*>(h + (size_t)n2 * DF) + lane);
        f32x4 x3 = __builtin_nontemporal_load(reinterpret_cast<const f32x4*>(x + (size_t)n3 * DF) + lane);
        f32x4 h3 = __builtin_nontemporal_load(reinterpret_cast<const f32x4*>(h + (size_t)n3 * DF) + lane);
        ax += x0 + x1 + x2 + x3;
        ah += h0 + h1 + h2 + h3;
    }
    for (; k < kmax; ++k) {
        int n0 = __shfl(nid, k);
        ax += __builtin_nontemporal_load(reinterpret_cast<const f32x4*>(x + (size_t)n0 * DF) + lane);
        ah += __builtin_nontemporal_load(reinterpret_cast<const f32x4*>(h + (size_t)n0 * DF) + lane);
    }
    // rare tail (len > 64): serial fallback
    for (int kk = 64; kk < len; ++kk) {
        int n0 = node_list[start + kk];
        ax += __builtin_nontemporal_load(reinterpret_cast<const f32x4*>(x + (size_t)n0 * DF) + lane);
        ah += __builtin_nontemporal_load(reinterpret_cast<const f32x4*>(h + (size_t)n0 * DF) + lane);
    }

    float inv = 1.0f / (float)(len > 0 ? len : 1);
    f32x4 vx = ax * inv;
    f32x4 vh = ah * inv;
    __builtin_nontemporal_store(vx, reinterpret_cast<f32x4*>(xp + (size_t)c * DF) + lane);
    __builtin_nontemporal_store(vh, reinterpret_cast<f32x4*>(hp + (size_t)c * DF) + lane);
}

// ---- 5. pos gather ----
__global__ void cp_pos(const float* __restrict__ pos, const int* __restrict__ sidx,
                       float* __restrict__ out, int C) {
    int i = blockIdx.x * blockDim.x + threadIdx.x;
    if (i >= C) return;
    int s = sidx[i];
    float p0 = pos[(size_t)s * 3 + 0];
    float p1 = pos[(size_t)s * 3 + 1];
    float p2 = pos[(size_t)s * 3 + 2];
    __builtin_nontemporal_store(p0, &out[(size_t)i * 3 + 0]);
    __builtin_nontemporal_store(p1, &out[(size_t)i * 3 + 1]);
    __builtin_nontemporal_store(p2, &out[(size_t)i * 3 + 2]);
}

extern "C" void kernel_launch(void* const* d_in, const int* in_sizes, int n_in,
                              void* d_out, int out_size, void* d_ws, size_t ws_size,
                              hipStream_t stream) {
    const float* x    = (const float*)d_in[0];
    const float* h    = (const float*)d_in[1];
    const float* pos  = (const float*)d_in[2];
    const int*   cmap = (const int*)d_in[3];
    const int*   sidx = (const int*)d_in[4];

    const int n_nodes = in_sizes[2] / 3;
    const int C       = in_sizes[4];

    float* out  = (float*)d_out;
    float* xp   = out;
    float* hp   = out + (size_t)C * DF;
    float* pout = out + (size_t)2 * C * DF;

    // ws ints: counts[C] | cursor[C] | offsets[C] | blocksums[256] | seg[2C] | node_list[N]
    int*  counts    = (int*)d_ws;
    int*  cursor    = counts + C;
    int*  offsets   = cursor + C;
    int*  blocksums = offsets + C;
    int2* seg       = (int2*)(blocksums + 256);
    int*  node_list = (int*)(seg + C);

    hipMemsetAsync(counts, 0, (size_t)2 * C * sizeof(int), stream);

    cp_count<<<(n_nodes + 255) / 256, 256, 0, stream>>>(cmap, counts, n_nodes);

    int nb = (C + 255) / 256;
    cp_scanA<<<nb, 256, 0, stream>>>(counts, offsets, blocksums, C);
    cp_scanB<<<1, 256, 0, stream>>>(blocksums, nb);
    cp_scanC<<<nb, 256, 0, stream>>>(offsets, blocksums, counts, seg, C);

    cp_fill<<<(n_nodes + 255) / 256, 256, 0, stream>>>(cmap, offsets, cursor, node_list, n_nodes);

    cp_pool<<<(C + 3) / 4, 256, 0, stream>>>(x, h, seg, node_list, xp, hp, C);

    cp_pos<<<(C + 255) / 256, 256, 0, stream>>>(pos, sidx, pout, C);
}

// Round 9
// 114.574 us; speedup vs baseline: 1.6932x; 1.1469x over previous
//
#include <hip/hip_runtime.h>

#define DF 256  // feature dim

typedef float f32x4 __attribute__((ext_vector_type(4)));

// ---- 1. histogram ----
__global__ void cp_count(const int* __restrict__ cmap, int* __restrict__ counts, int n) {
    int i = blockIdx.x * blockDim.x + threadIdx.x;
    if (i < n) atomicAdd(&counts[cmap[i]], 1);
}

// ---- 2a. per-block exclusive scan ----
__global__ void cp_scanA(const int* __restrict__ counts, int* __restrict__ offsets,
                         int* __restrict__ blocksums, int C) {
    __shared__ int s[256];
    int tid = threadIdx.x;
    int i = blockIdx.x * 256 + tid;
    int v = (i < C) ? counts[i] : 0;
    s[tid] = v;
    __syncthreads();
    for (int off = 1; off < 256; off <<= 1) {
        int t = (tid >= off) ? s[tid - off] : 0;
        __syncthreads();
        s[tid] += t;
        __syncthreads();
    }
    if (i < C) offsets[i] = s[tid] - v;
    if (tid == 255) blocksums[blockIdx.x] = s[255];
}

// ---- 2b. scan block sums ----
__global__ void cp_scanB(int* __restrict__ blocksums, int nb) {
    __shared__ int s[256];
    int tid = threadIdx.x;
    if (nb <= 256) {
        int v = (tid < nb) ? blocksums[tid] : 0;
        s[tid] = v;
        __syncthreads();
        for (int off = 1; off < 256; off <<= 1) {
            int t = (tid >= off) ? s[tid - off] : 0;
            __syncthreads();
            s[tid] += t;
            __syncthreads();
        }
        if (tid < nb) blocksums[tid] = s[tid] - v;
    } else if (tid == 0) {
        int run = 0;
        for (int k = 0; k < nb; ++k) { int t = blocksums[k]; blocksums[k] = run; run += t; }
    }
}

// ---- 2c. add block offsets; also build fused seg[c] = {start, len} ----
__global__ void cp_scanC(int* __restrict__ offsets, const int* __restrict__ blocksums,
                         const int* __restrict__ counts, int2* __restrict__ seg, int C) {
    int i = blockIdx.x * 256 + threadIdx.x;
    if (i < C) {
        int st = offsets[i] + blocksums[blockIdx.x];
        offsets[i] = st;
        seg[i] = make_int2(st, counts[i]);
    }
}

// ---- 3. bucket-fill ----
__global__ void cp_fill(const int* __restrict__ cmap, const int* __restrict__ offsets,
                        int* __restrict__ cursor, int* __restrict__ node_list, int n) {
    int i = blockIdx.x * blockDim.x + threadIdx.x;
    if (i < n) {
        int c = cmap[i];
        int slot = atomicAdd(&cursor[c], 1);
        node_list[offsets[c] + slot] = i;
    }
}

// ---- 4. pool: dual-path gather — x cached (L3-resident), h non-temporal (HBM) ----
__global__ void cp_pool(const float* __restrict__ x, const float* __restrict__ h,
                        const int2* __restrict__ seg, const int* __restrict__ node_list,
                        float* __restrict__ xp, float* __restrict__ hp, int C) {
    int c = blockIdx.x * 4 + (threadIdx.x >> 6);
    if (c >= C) return;
    int lane = threadIdx.x & 63;
    int2 sl = seg[c];                      // one 8B load: {start, len}
    int start = sl.x, len = sl.y;

    // preload up to 64 node ids in a single coalesced vector load
    int nid = 0;
    if (lane < len) nid = node_list[start + lane];

    f32x4 ax = 0.f;
    f32x4 ah = 0.f;
    int kmax = len < 64 ? len : 64;
    int k = 0;
    for (; k + 4 <= kmax; k += 4) {
        int n0 = __shfl(nid, k);
        int n1 = __shfl(nid, k + 1);
        int n2 = __shfl(nid, k + 2);
        int n3 = __shfl(nid, k + 3);
        f32x4 x0 = reinterpret_cast<const f32x4*>(x + (size_t)n0 * DF)[lane];           // cached
        f32x4 h0 = __builtin_nontemporal_load(reinterpret_cast<const f32x4*>(h + (size_t)n0 * DF) + lane);
        f32x4 x1 = reinterpret_cast<const f32x4*>(x + (size_t)n1 * DF)[lane];
        f32x4 h1 = __builtin_nontemporal_load(reinterpret_cast<const f32x4*>(h + (size_t)n1 * DF) + lane);
        f32x4 x2 = reinterpret_cast<const f32x4*>(x + (size_t)n2 * DF)[lane];
        f32x4 h2 = __builtin_nontemporal_load(reinterpret_cast<const f32x4*>(h + (size_t)n2 * DF) + lane);
        f32x4 x3 = reinterpret_cast<const f32x4*>(x + (size_t)n3 * DF)[lane];
        f32x4 h3 = __builtin_nontemporal_load(reinterpret_cast<const f32x4*>(h + (size_t)n3 * DF) + lane);
        ax += x0 + x1 + x2 + x3;
        ah += h0 + h1 + h2 + h3;
    }
    for (; k < kmax; ++k) {
        int n0 = __shfl(nid, k);
        ax += reinterpret_cast<const f32x4*>(x + (size_t)n0 * DF)[lane];
        ah += __builtin_nontemporal_load(reinterpret_cast<const f32x4*>(h + (size_t)n0 * DF) + lane);
    }
    // rare tail (len > 64): serial fallback
    for (int kk = 64; kk < len; ++kk) {
        int n0 = node_list[start + kk];
        ax += reinterpret_cast<const f32x4*>(x + (size_t)n0 * DF)[lane];
        ah += __builtin_nontemporal_load(reinterpret_cast<const f32x4*>(h + (size_t)n0 * DF) + lane);
    }

    float inv = 1.0f / (float)(len > 0 ? len : 1);
    f32x4 vx = ax * inv;
    f32x4 vh = ah * inv;
    __builtin_nontemporal_store(vx, reinterpret_cast<f32x4*>(xp + (size_t)c * DF) + lane);
    __builtin_nontemporal_store(vh, reinterpret_cast<f32x4*>(hp + (size_t)c * DF) + lane);
}

// ---- 5. pos gather ----
__global__ void cp_pos(const float* __restrict__ pos, const int* __restrict__ sidx,
                       float* __restrict__ out, int C) {
    int i = blockIdx.x * blockDim.x + threadIdx.x;
    if (i >= C) return;
    int s = sidx[i];
    float p0 = pos[(size_t)s * 3 + 0];
    float p1 = pos[(size_t)s * 3 + 1];
    float p2 = pos[(size_t)s * 3 + 2];
    __builtin_nontemporal_store(p0, &out[(size_t)i * 3 + 0]);
    __builtin_nontemporal_store(p1, &out[(size_t)i * 3 + 1]);
    __builtin_nontemporal_store(p2, &out[(size_t)i * 3 + 2]);
}

extern "C" void kernel_launch(void* const* d_in, const int* in_sizes, int n_in,
                              void* d_out, int out_size, void* d_ws, size_t ws_size,
                              hipStream_t stream) {
    const float* x    = (const float*)d_in[0];
    const float* h    = (const float*)d_in[1];
    const float* pos  = (const float*)d_in[2];
    const int*   cmap = (const int*)d_in[3];
    const int*   sidx = (const int*)d_in[4];

    const int n_nodes = in_sizes[2] / 3;
    const int C       = in_sizes[4];

    float* out  = (float*)d_out;
    float* xp   = out;
    float* hp   = out + (size_t)C * DF;
    float* pout = out + (size_t)2 * C * DF;

    // ws ints: counts[C] | cursor[C] | offsets[C] | blocksums[256] | seg[2C] | node_list[N]
    int*  counts    = (int*)d_ws;
    int*  cursor    = counts + C;
    int*  offsets   = cursor + C;
    int*  blocksums = offsets + C;
    int2* seg       = (int2*)(blocksums + 256);
    int*  node_list = (int*)(seg + C);

    hipMemsetAsync(counts, 0, (size_t)2 * C * sizeof(int), stream);

    cp_count<<<(n_nodes + 255) / 256, 256, 0, stream>>>(cmap, counts, n_nodes);

    int nb = (C + 255) / 256;
    cp_scanA<<<nb, 256, 0, stream>>>(counts, offsets, blocksums, C);
    cp_scanB<<<1, 256, 0, stream>>>(blocksums, nb);
    cp_scanC<<<nb, 256, 0, stream>>>(offsets, blocksums, counts, seg, C);

    cp_fill<<<(n_nodes + 255) / 256, 256, 0, stream>>>(cmap, offsets, cursor, node_list, n_nodes);

    cp_pool<<<(C + 3) / 4, 256, 0, stream>>>(x, h, seg, node_list, xp, hp, C);

    cp_pos<<<(C + 255) / 256, 256, 0, stream>>>(pos, sidx, pout, C);
}

// Round 10
// 112.514 us; speedup vs baseline: 1.7242x; 1.0183x over previous
//
#include <hip/hip_runtime.h>

#define DF 256  // feature dim

typedef float f32x4 __attribute__((ext_vector_type(4)));

// ---- 1. histogram ----
__global__ void cp_count(const int* __restrict__ cmap, int* __restrict__ counts, int n) {
    int i = blockIdx.x * blockDim.x + threadIdx.x;
    if (i < n) atomicAdd(&counts[cmap[i]], 1);
}

// ---- 2. fused scan: block-local prefix + atomic base grab.
//         Bucket ORDER across blocks is irrelevant — seg[c] records each
//         cluster's {start,len}, so any disjoint partition of node_list works.
__global__ void cp_scan(const int* __restrict__ counts, int* __restrict__ tail,
                        int2* __restrict__ seg, int* __restrict__ cursor, int C) {
    __shared__ int s[256];
    __shared__ int base;
    int tid = threadIdx.x;
    int i = blockIdx.x * 256 + tid;
    int v = (i < C) ? counts[i] : 0;
    s[tid] = v;
    __syncthreads();
    for (int off = 1; off < 256; off <<= 1) {
        int t = (tid >= off) ? s[tid - off] : 0;
        __syncthreads();
        s[tid] += t;
        __syncthreads();
    }
    if (tid == 255) base = atomicAdd(tail, s[255]);
    __syncthreads();
    if (i < C) {
        int st = base + s[tid] - v;   // exclusive within block + block base
        cursor[i] = st;
        seg[i] = make_int2(st, v);
    }
}

// ---- 3. bucket-fill (cursor pre-initialized to start offsets) ----
__global__ void cp_fill(const int* __restrict__ cmap, int* __restrict__ cursor,
                        int* __restrict__ node_list, int n) {
    int i = blockIdx.x * blockDim.x + threadIdx.x;
    if (i < n) {
        int pos = atomicAdd(&cursor[cmap[i]], 1);
        node_list[pos] = i;
    }
}

// ---- 4. pool (dual-path gather: x cached/L3, h non-temporal/HBM) + fused pos gather ----
__global__ void cp_pool(const float* __restrict__ x, const float* __restrict__ h,
                        const int2* __restrict__ seg, const int* __restrict__ node_list,
                        float* __restrict__ xp, float* __restrict__ hp, int C,
                        int poolBlocks,
                        const float* __restrict__ pos, const int* __restrict__ sidx,
                        float* __restrict__ pout) {
    if (blockIdx.x >= poolBlocks) {
        // ---- pos gather tail blocks ----
        int i = (blockIdx.x - poolBlocks) * blockDim.x + threadIdx.x;
        if (i < C) {
            int s = sidx[i];
            float p0 = pos[(size_t)s * 3 + 0];
            float p1 = pos[(size_t)s * 3 + 1];
            float p2 = pos[(size_t)s * 3 + 2];
            __builtin_nontemporal_store(p0, &pout[(size_t)i * 3 + 0]);
            __builtin_nontemporal_store(p1, &pout[(size_t)i * 3 + 1]);
            __builtin_nontemporal_store(p2, &pout[(size_t)i * 3 + 2]);
        }
        return;
    }

    int c = blockIdx.x * 4 + (threadIdx.x >> 6);
    if (c >= C) return;
    int lane = threadIdx.x & 63;
    int2 sl = seg[c];
    int start = sl.x, len = sl.y;

    // preload up to 64 node ids in a single coalesced vector load
    int nid = 0;
    if (lane < len) nid = node_list[start + lane];

    f32x4 ax = 0.f;
    f32x4 ah = 0.f;
    int kmax = len < 64 ? len : 64;
    int k = 0;
    for (; k + 4 <= kmax; k += 4) {
        int n0 = __shfl(nid, k);
        int n1 = __shfl(nid, k + 1);
        int n2 = __shfl(nid, k + 2);
        int n3 = __shfl(nid, k + 3);
        f32x4 x0 = reinterpret_cast<const f32x4*>(x + (size_t)n0 * DF)[lane];           // cached
        f32x4 h0 = __builtin_nontemporal_load(reinterpret_cast<const f32x4*>(h + (size_t)n0 * DF) + lane);
        f32x4 x1 = reinterpret_cast<const f32x4*>(x + (size_t)n1 * DF)[lane];
        f32x4 h1 = __builtin_nontemporal_load(reinterpret_cast<const f32x4*>(h + (size_t)n1 * DF) + lane);
        f32x4 x2 = reinterpret_cast<const f32x4*>(x + (size_t)n2 * DF)[lane];
        f32x4 h2 = __builtin_nontemporal_load(reinterpret_cast<const f32x4*>(h + (size_t)n2 * DF) + lane);
        f32x4 x3 = reinterpret_cast<const f32x4*>(x + (size_t)n3 * DF)[lane];
        f32x4 h3 = __builtin_nontemporal_load(reinterpret_cast<const f32x4*>(h + (size_t)n3 * DF) + lane);
        ax += x0 + x1 + x2 + x3;
        ah += h0 + h1 + h2 + h3;
    }
    for (; k < kmax; ++k) {
        int n0 = __shfl(nid, k);
        ax += reinterpret_cast<const f32x4*>(x + (size_t)n0 * DF)[lane];
        ah += __builtin_nontemporal_load(reinterpret_cast<const f32x4*>(h + (size_t)n0 * DF) + lane);
    }
    // rare tail (len > 64): serial fallback
    for (int kk = 64; kk < len; ++kk) {
        int n0 = node_list[start + kk];
        ax += reinterpret_cast<const f32x4*>(x + (size_t)n0 * DF)[lane];
        ah += __builtin_nontemporal_load(reinterpret_cast<const f32x4*>(h + (size_t)n0 * DF) + lane);
    }

    float inv = 1.0f / (float)(len > 0 ? len : 1);
    f32x4 vx = ax * inv;
    f32x4 vh = ah * inv;
    __builtin_nontemporal_store(vx, reinterpret_cast<f32x4*>(xp + (size_t)c * DF) + lane);
    __builtin_nontemporal_store(vh, reinterpret_cast<f32x4*>(hp + (size_t)c * DF) + lane);
}

extern "C" void kernel_launch(void* const* d_in, const int* in_sizes, int n_in,
                              void* d_out, int out_size, void* d_ws, size_t ws_size,
                              hipStream_t stream) {
    const float* x    = (const float*)d_in[0];
    const float* h    = (const float*)d_in[1];
    const float* pos  = (const float*)d_in[2];
    const int*   cmap = (const int*)d_in[3];
    const int*   sidx = (const int*)d_in[4];

    const int n_nodes = in_sizes[2] / 3;
    const int C       = in_sizes[4];

    float* out  = (float*)d_out;
    float* xp   = out;
    float* hp   = out + (size_t)C * DF;
    float* pout = out + (size_t)2 * C * DF;

    // ws ints: counts[C] | tail[1] | cursor[C] | seg[2C] | node_list[N]
    int*  counts    = (int*)d_ws;
    int*  tail      = counts + C;
    int*  cursor    = tail + 1;
    int2* seg       = (int2*)(cursor + C);
    int*  node_list = (int*)(seg + C);

    // zero counts + tail each call (d_ws is not re-poisoned between replays)
    hipMemsetAsync(counts, 0, (size_t)(C + 1) * sizeof(int), stream);

    cp_count<<<(n_nodes + 255) / 256, 256, 0, stream>>>(cmap, counts, n_nodes);

    int nb = (C + 255) / 256;
    cp_scan<<<nb, 256, 0, stream>>>(counts, tail, seg, cursor, C);

    cp_fill<<<(n_nodes + 255) / 256, 256, 0, stream>>>(cmap, cursor, node_list, n_nodes);

    int poolBlocks = (C + 3) / 4;
    int posBlocks  = (C + 255) / 256;
    cp_pool<<<poolBlocks + posBlocks, 256, 0, stream>>>(
        x, h, seg, node_list, xp, hp, C, poolBlocks, pos, sidx, pout);
}